// Round 1
// 113.665 us; speedup vs baseline: 1.0056x; 1.0056x over previous
//
#include <hip/hip_runtime.h>

typedef __bf16 bf16x8 __attribute__((ext_vector_type(8)));
typedef __bf16 bf16x4 __attribute__((ext_vector_type(4)));
typedef float f32x4 __attribute__((ext_vector_type(4)));
typedef short s16x4 __attribute__((ext_vector_type(4)));

#define NB 4
#define NC 64
#define NN 4096
#define SPLIT 8   // key-dim splits for flash

// sc folded into Q at qkv time: softmax uses exp2(q.k * 0.125 * log2(e))
#define QSCALE (0.125f * 1.44269504088896340736f)

#if __has_builtin(__builtin_amdgcn_exp2f)
#define EXP2(x) __builtin_amdgcn_exp2f(x)   // raw v_exp_f32; inputs are O(1)
#else
#define EXP2(x) exp2f(x)
#endif

// direct global->LDS, 16B/lane; dst must be WAVE-UNIFORM base (HW adds lane*16),
// src is per-lane (this is where the swizzle lives).
#define GLL16(src, dst)                                                  \
  __builtin_amdgcn_global_load_lds(                                      \
      (const __attribute__((address_space(1))) void*)(src),              \
      (__attribute__((address_space(3))) void*)(dst), 16, 0, 0)

// ---------------------------------------------------------------------------
// Kernel 1: QKV projection via MFMA, LDS-free, barrier-free.  (unchanged)
// ---------------------------------------------------------------------------
__global__ __launch_bounds__(256) void qkv_kernel(
    const float* __restrict__ x, const float* __restrict__ wqkv,
    const float* __restrict__ bqkv,
    __bf16* __restrict__ Qg, __bf16* __restrict__ Kg, __bf16* __restrict__ Vg)
{
  const int tid = threadIdx.x;
  const int wave = tid >> 6;
  const int lane = tid & 63;
  const int quad = lane >> 4;
  const int l16 = lane & 15;
  const int b = blockIdx.y;
  const int tsel = blockIdx.z;                 // 0=q, 1=k, 2=v
  const int n0 = blockIdx.x * 128 + wave * 32; // wave's 32 n
  const float wscale = (tsel == 0) ? QSCALE : 1.0f;

  // preload W^T B-frags: [ot][ch]; oc = ot*16+l16, c = ch*32+quad*8+j
  bf16x8 wf[4][2];
#pragma unroll
  for (int ot = 0; ot < 4; ot++) {
#pragma unroll
    for (int ch = 0; ch < 2; ch++) {
      const float* wp =
          wqkv + (size_t)(tsel * 64 + ot * 16 + l16) * 64 + ch * 32 + quad * 8;
      const float4 w0 = *(const float4*)wp;
      const float4 w1 = *(const float4*)(wp + 4);
      bf16x8 f;
      f[0] = (__bf16)(w0.x * wscale); f[1] = (__bf16)(w0.y * wscale);
      f[2] = (__bf16)(w0.z * wscale); f[3] = (__bf16)(w0.w * wscale);
      f[4] = (__bf16)(w1.x * wscale); f[5] = (__bf16)(w1.y * wscale);
      f[6] = (__bf16)(w1.z * wscale); f[7] = (__bf16)(w1.w * wscale);
      wf[ot][ch] = f;
    }
  }
  float bv[4];
#pragma unroll
  for (int ot = 0; ot < 4; ot++)
    bv[ot] = bqkv[tsel * 64 + ot * 16 + l16] * wscale;

#pragma unroll
  for (int nt = 0; nt < 2; nt++) {
    const int nb = n0 + nt * 16 + l16;

    // A-frags: x^T[n][c] for c-halves; direct global, 4 lines/instr
    bf16x8 xf[2];
#pragma unroll
    for (int ch = 0; ch < 2; ch++) {
      float v[8];
#pragma unroll
      for (int j = 0; j < 8; j++)
        v[j] = x[(size_t)(b * 64 + ch * 32 + quad * 8 + j) * NN + nb];
      bf16x8 f;
#pragma unroll
      for (int j = 0; j < 8; j++) f[j] = (__bf16)v[j];
      xf[ch] = f;
    }

#pragma unroll
    for (int ot = 0; ot < 4; ot++) {
      f32x4 acc = (f32x4){bv[ot], bv[ot], bv[ot], bv[ot]};
      acc = __builtin_amdgcn_mfma_f32_16x16x32_bf16(xf[0], wf[ot][0], acc, 0, 0, 0);
      acc = __builtin_amdgcn_mfma_f32_16x16x32_bf16(xf[1], wf[ot][1], acc, 0, 0, 0);

      if (tsel < 2) {
        __bf16* dst = (tsel == 0) ? Qg : Kg;
#pragma unroll
        for (int r = 0; r < 4; r++)
          dst[(size_t)(b * NN + n0 + nt * 16 + quad * 4 + r) * 64 + ot * 16 + l16] =
              (__bf16)acc[r];
      } else {
        bf16x4 pv;
#pragma unroll
        for (int r = 0; r < 4; r++) pv[r] = (__bf16)acc[r];
        *(bf16x4*)(Vg + (size_t)(b * 64 + ot * 16 + l16) * NN +
                   n0 + nt * 16 + quad * 4) = pv;
      }
    }
  }
}

// ---------------------------------------------------------------------------
// Kernel 2: flash attention, split-K, max-free softmax, FUSED PROJ EPILOGUE.
// v2: double-buffered K/V LDS staged with global_load_lds_dwordx4 (16B/lane),
// involutive chunk-XOR swizzle (chunk' = chunk ^ (row&7)) applied on the
// per-lane GLOBAL source and on the LDS READ side; LDS dest stays linear
// (rule #21).  Per tile: issue next-tile stage -> compute current -> ONE
// __syncthreads() (its vmcnt(0)/lgkmcnt(0) drain lands after ~1500 cyc of
// MFMA+exp compute, hiding the K/V fetch latency).  1 barrier/tile (was 2,
// with the drain BEFORE compute).  Math identical to v1.
// Bank balance (derived): K-read b128 -> 8 lanes per 16B slot (balanced);
// V-read b64 -> 4 lanes per 8B slot (balanced); same as the old 72-pad tiles.
// grid(32, B, SPLIT), 256 thr = 4 waves; wave owns 32 q, block 128 q.
// LDS = 2*(8KB K + 8KB V) = 32 KB -> 4 blocks/CU.
// ---------------------------------------------------------------------------
__global__ __launch_bounds__(256) void flash_kernel(
    const __bf16* __restrict__ Q, const __bf16* __restrict__ K,
    const __bf16* __restrict__ V, const float* __restrict__ wproj,
    __bf16* __restrict__ Opart, float* __restrict__ lpart)
{
  const int b = blockIdx.y;
  const int s = blockIdx.z;
  const int tid = threadIdx.x;
  const int wave = tid >> 6;
  const int lane = tid & 63;
  const int quad = lane >> 4;
  const int l16 = lane & 15;

  __shared__ __bf16 KB[2][64 * 64];   // [buf][key][c], chunk-swizzled
  __shared__ __bf16 VB[2][64 * 64];   // [buf][c][key], chunk-swizzled

  const int q0 = blockIdx.x * 128 + wave * 32;

  bf16x8 qf[2][2];
#pragma unroll
  for (int qt = 0; qt < 2; qt++) {
    const __bf16* qrow = Q + ((size_t)(b * NN + q0 + qt * 16 + l16)) * 64;
    qf[qt][0] = *(const bf16x8*)(qrow + quad * 8);
    qf[qt][1] = *(const bf16x8*)(qrow + 32 + quad * 8);
  }

  // ---- swizzled READ offsets (elements within a 64-elem row) -------------
  // row&7 == l16&7 for every row we read (rows are t*16 + l16).
  const int h = l16 & 7;
  const int ko0 = (quad ^ h) << 3;          // logical chunk quad
  const int ko1 = ((quad + 4) ^ h) << 3;    // logical chunk quad+4
  int vo[4];                                 // PV b64 read: chunk 2kg+(quad>>1)
#pragma unroll
  for (int kg = 0; kg < 4; kg++)
    vo[kg] = ((((kg << 1) + (quad >> 1)) ^ h) << 3) + ((quad & 1) << 2);

  // ---- staging geometry: 512 16B-chunks per tensor tile; wave w owns
  // chunks [w*128, w*128+128) as 2 instrs of 64 lanes.  LDS linear in chunk;
  // global source pre-swizzled: chunk c -> row r=c>>3, col chunk (c&7)^(r&7).
  const int c0 = wave * 128 + lane;
  const int c1 = c0 + 64;
  const int r0 = c0 >> 3, r1 = c1 >> 3;
  const int k0 = (c0 & 7) ^ (r0 & 7);
  const int k1 = (c1 & 7) ^ (r1 & 7);
  const int kbeg = s * (NN / SPLIT);
  const __bf16* Ks0 = K + ((size_t)b * NN + kbeg + r0) * 64 + k0 * 8;
  const __bf16* Ks1 = K + ((size_t)b * NN + kbeg + r1) * 64 + k1 * 8;
  const __bf16* Vs0 = V + ((size_t)(b * 64 + r0)) * NN + kbeg + k0 * 8;
  const __bf16* Vs1 = V + ((size_t)(b * 64 + r1)) * NN + kbeg + k1 * 8;
  const int db0 = wave * 128 * 8;           // element offset of chunk w*128
  const int db1 = db0 + 64 * 8;

  // ---- prologue: stage tile 0 into buf 0 ---------------------------------
  GLL16(Ks0, &KB[0][db0]);
  GLL16(Ks1, &KB[0][db1]);
  GLL16(Vs0, &VB[0][db0]);
  GLL16(Vs1, &VB[0][db1]);

  f32x4 acc[2][4];    // O^T acc: row c = ct*16+quad*4+r, col q = qt*16+l16
#pragma unroll
  for (int qt = 0; qt < 2; qt++)
#pragma unroll
    for (int ct = 0; ct < 4; ct++) acc[qt][ct] = (f32x4){0.f, 0.f, 0.f, 0.f};
  float l[2] = {0.f, 0.f};

  __syncthreads();    // compiler drains vmcnt(0): tile 0 resident

  const int NT = (NN / SPLIT) / 64;   // 8 tiles
  int cur = 0;
#pragma unroll 1
  for (int t8 = 0; t8 < NT; t8++) {
    // ---- issue next tile's stage FIRST (latency hides under compute) ----
    if (t8 + 1 < NT) {
      const int nb = cur ^ 1;
      const size_t kadv = (size_t)(t8 + 1) * 64 * 64;  // K rows advance
      const int vadv = (t8 + 1) * 64;                   // V cols advance
      GLL16(Ks0 + kadv, &KB[nb][db0]);
      GLL16(Ks1 + kadv, &KB[nb][db1]);
      GLL16(Vs0 + vadv, &VB[nb][db0]);
      GLL16(Vs1 + vadv, &VB[nb][db1]);
    }
    const __bf16* Kb = KB[cur];
    const __bf16* Vb = VB[cur];

    // ---- S^T = K Q^T, P packed into registers --------------------------
    s16x4 pk[4][2];
#pragma unroll
    for (int t = 0; t < 4; t++) {
      const __bf16* krow = Kb + (t * 16 + l16) * 64;
      const bf16x8 kf0 = *(const bf16x8*)(krow + ko0);
      const bf16x8 kf1 = *(const bf16x8*)(krow + ko1);
#pragma unroll
      for (int qt = 0; qt < 2; qt++) {
        f32x4 z = (f32x4){0.f, 0.f, 0.f, 0.f};
        z = __builtin_amdgcn_mfma_f32_16x16x32_bf16(kf0, qf[qt][0], z, 0, 0, 0);
        z = __builtin_amdgcn_mfma_f32_16x16x32_bf16(kf1, qf[qt][1], z, 0, 0, 0);
        const float p0 = EXP2(z[0]), p1 = EXP2(z[1]);
        const float p2 = EXP2(z[2]), p3 = EXP2(z[3]);
        l[qt] += (p0 + p1) + (p2 + p3);
        bf16x4 pv;
        pv[0] = (__bf16)p0; pv[1] = (__bf16)p1;
        pv[2] = (__bf16)p2; pv[3] = (__bf16)p3;
        pk[t][qt] = __builtin_bit_cast(s16x4, pv);
      }
    }

    // ---- O^T += V^T P^T : K=16 MFMAs, P straight from registers --------
#pragma unroll
    for (int kg = 0; kg < 4; kg++) {
#pragma unroll
      for (int ct = 0; ct < 4; ct++) {
        const bf16x4 va =
            *(const bf16x4*)(Vb + (ct * 16 + l16) * 64 + vo[kg]);
        const s16x4 a = __builtin_bit_cast(s16x4, va);
        acc[0][ct] = __builtin_amdgcn_mfma_f32_16x16x16bf16_1k(
            a, pk[kg][0], acc[0][ct], 0, 0, 0);
        acc[1][ct] = __builtin_amdgcn_mfma_f32_16x16x16bf16_1k(
            a, pk[kg][1], acc[1][ct], 0, 0, 0);
      }
    }

    // ---- one barrier/tile: drains next-tile loads AFTER compute --------
    if (t8 + 1 < NT) __syncthreads();
    cur ^= 1;
  }

  // ---- epilogue 1: l reduction (2 shuffles per q-tile) ------------------
#pragma unroll
  for (int qt = 0; qt < 2; qt++) {
    float lr = l[qt];
    lr += __shfl_xor(lr, 16);
    lr += __shfl_xor(lr, 32);
    if (quad == 0)
      lpart[((size_t)(s * NB + b)) * NN + q0 + qt * 16 + l16] = lr;
  }

  // ---- epilogue 2: fused proj.  Po^T = Wp * O^T -------------------------
  s16x4 ob[2][4];
#pragma unroll
  for (int qt = 0; qt < 2; qt++)
#pragma unroll
    for (int ch = 0; ch < 4; ch++) {
      bf16x4 t;
#pragma unroll
      for (int r = 0; r < 4; r++) t[r] = (__bf16)acc[qt][ch][r];
      ob[qt][ch] = __builtin_bit_cast(s16x4, t);
    }

#pragma unroll
  for (int cot = 0; cot < 4; cot++) {
    f32x4 po[2];
    po[0] = (f32x4){0.f, 0.f, 0.f, 0.f};
    po[1] = (f32x4){0.f, 0.f, 0.f, 0.f};
#pragma unroll
    for (int ch = 0; ch < 4; ch++) {
      const float4 wv =
          *(const float4*)&wproj[(cot * 16 + l16) * 64 + ch * 16 + quad * 4];
      bf16x4 wb;
      wb[0] = (__bf16)wv.x; wb[1] = (__bf16)wv.y;
      wb[2] = (__bf16)wv.z; wb[3] = (__bf16)wv.w;
      const s16x4 a = __builtin_bit_cast(s16x4, wb);
      po[0] = __builtin_amdgcn_mfma_f32_16x16x16bf16_1k(a, ob[0][ch], po[0], 0, 0, 0);
      po[1] = __builtin_amdgcn_mfma_f32_16x16x16bf16_1k(a, ob[1][ch], po[1], 0, 0, 0);
    }
#pragma unroll
    for (int qt = 0; qt < 2; qt++)
#pragma unroll
      for (int r = 0; r < 4; r++)
        Opart[(((size_t)(s * NB + b)) * 64 + cot * 16 + quad * 4 + r) * NN +
              q0 + qt * 16 + l16] = (__bf16)po[qt][r];
  }
}

// ---------------------------------------------------------------------------
// Kernel 3: slim combine — sum proj-space split partials, 1/l, + bias +
// residual.  (unchanged)
// ---------------------------------------------------------------------------
__global__ __launch_bounds__(256) void combine_kernel(
    const __bf16* __restrict__ Opart, const float* __restrict__ lpart,
    const float* __restrict__ bproj, const float* __restrict__ x,
    float* __restrict__ out)
{
  const int b = blockIdx.y;
  const int n0 = blockIdx.x * 32;
  const int tid = threadIdx.x;

  __shared__ float linv[32];
  if (tid < 32) {
    float lt = 0.f;
#pragma unroll
    for (int s = 0; s < SPLIT; s++)
      lt += lpart[((size_t)(s * NB + b)) * NN + n0 + tid];
    linv[tid] = 1.0f / lt;
  }
  __syncthreads();

  const int c = tid >> 2;
  const int n8 = (tid & 3) * 8;

  float o[8];
#pragma unroll
  for (int j = 0; j < 8; j++) o[j] = 0.f;
#pragma unroll
  for (int s = 0; s < SPLIT; s++) {
    const bf16x8 v = *(const bf16x8*)(
        Opart + (((size_t)(s * NB + b)) * 64 + c) * NN + n0 + n8);
#pragma unroll
    for (int j = 0; j < 8; j++) o[j] += (float)v[j];
  }

  const float bb = bproj[c];
  const float4 li0 = *(const float4*)&linv[n8];
  const float4 li1 = *(const float4*)&linv[n8 + 4];
  const size_t base = ((size_t)(b * 64 + c)) * NN + n0 + n8;
  const float4 x0 = *(const float4*)&x[base];
  const float4 x1 = *(const float4*)&x[base + 4];
  float4 r0, r1;
  r0.x = o[0] * li0.x + bb + x0.x;  r0.y = o[1] * li0.y + bb + x0.y;
  r0.z = o[2] * li0.z + bb + x0.z;  r0.w = o[3] * li0.w + bb + x0.w;
  r1.x = o[4] * li1.x + bb + x1.x;  r1.y = o[5] * li1.y + bb + x1.y;
  r1.z = o[6] * li1.z + bb + x1.z;  r1.w = o[7] * li1.w + bb + x1.w;
  *(float4*)&out[base] = r0;
  *(float4*)&out[base + 4] = r1;
}

extern "C" void kernel_launch(void* const* d_in, const int* in_sizes, int n_in,
                              void* d_out, int out_size, void* d_ws, size_t ws_size,
                              hipStream_t stream) {
  const float* x     = (const float*)d_in[0];
  const float* wqkv  = (const float*)d_in[1];
  const float* bqkv  = (const float*)d_in[2];
  const float* wproj = (const float*)d_in[3];
  const float* bproj = (const float*)d_in[4];
  float* out = (float*)d_out;

  // Workspace: Q[0,2M) K[2,4M) V[4,6M) Opart[6,22M) lpart[23,23.5M)
  char* ws = (char*)d_ws;
  __bf16* Q     = (__bf16*)(ws);
  __bf16* K     = (__bf16*)(ws + (2u << 20));
  __bf16* V     = (__bf16*)(ws + (4u << 20));
  __bf16* Opart = (__bf16*)(ws + (6u << 20));   // [S,B,C,N] = 16 MiB
  float*  lpart = (float*)(ws + (23u << 20));   // SPLIT*B*N*4 = 512 KiB

  qkv_kernel<<<dim3(32, NB, 3), 256, 0, stream>>>(x, wqkv, bqkv, Q, K, V);
  flash_kernel<<<dim3(32, NB, SPLIT), 256, 0, stream>>>(Q, K, V, wproj,
                                                        Opart, lpart);
  combine_kernel<<<dim3(128, NB), 256, 0, stream>>>(Opart, lpart, bproj, x,
                                                    out);
}